// Round 6
// baseline (702.977 us; speedup 1.0000x reference)
//
#include <hip/hip_runtime.h>

#define DEVI static __device__ __forceinline__

typedef __attribute__((ext_vector_type(4))) float f32x4;
typedef __attribute__((ext_vector_type(8))) __bf16 bf16x8;
typedef __attribute__((ext_vector_type(8))) unsigned short u16x8;
typedef __attribute__((ext_vector_type(4))) unsigned short u16x4;
typedef __attribute__((ext_vector_type(2))) unsigned short u16x2;

DEVI unsigned short f2bf(float f) {
  union { float f; unsigned int u; } v; v.f = f;
  unsigned int u = v.u;
  u += 0x7FFFu + ((u >> 16) & 1u);   // RNE
  return (unsigned short)(u >> 16);
}
DEVI float bf2f(unsigned short s) {
  union { unsigned int u; float f; } v; v.u = ((unsigned int)s) << 16;
  return v.f;
}
// branch-free fast sigmoid/tanh: 2 trans + 2-3 VALU each, correct saturation
DEVI float sigf(float x) {
  return __builtin_amdgcn_rcpf(1.0f + __builtin_amdgcn_exp2f(-1.44269504089f * x));
}
DEVI float tanhf_(float x) {
  return 1.0f - 2.0f * __builtin_amdgcn_rcpf(1.0f + __builtin_amdgcn_exp2f(2.88539008178f * x));
}
DEVI f32x4 mfma_bf16(bf16x8 a, bf16x8 b, f32x4 c) {
  return __builtin_amdgcn_mfma_f32_16x16x32_bf16(a, b, c, 0, 0, 0);
}
DEVI f32x4 mfma_fp8(long a, long b, f32x4 c) {
  return __builtin_amdgcn_mfma_f32_16x16x32_fp8_fp8(a, b, c, 0, 0, 0);
}
// LDS-only barrier: does NOT drain vmcnt (global stores/prefetch stay in
// flight across the barrier) — verified plain-HIP pattern (8-phase template).
DEVI void lds_barrier() {
  asm volatile("s_waitcnt lgkmcnt(0)" ::: "memory");
  __builtin_amdgcn_s_barrier();
}

// ---------------- K0a: wWih_{f,b} f32 -> bf16, concat rows [2048][640] ----
__global__ void k_cast_wih(const float* wf, const float* wb, unsigned short* out) {
  int i = blockIdx.x * 256 + threadIdx.x;   // 2048*640 = 1,310,720
  if (i < 2048 * 640) {
    int r = i / 640, c = i - r * 640;
    float v = (r < 1024) ? wf[r * 640 + c] : wb[(r - 1024) * 640 + c];
    out[i] = f2bf(v);
  }
}

// ---------------- K0b: wWhh_{f,b} f32 -> fp8 e4m3 (x16 scale) [2][1024][256]
__global__ void k_cast_whh(const float* wf, const float* wb, unsigned short* out) {
  int i = blockIdx.x * 256 + threadIdx.x;   // pairs: 524288/2 = 262144
  if (i < 262144) {
    int e = i * 2;
    const float* src = (e < 262144) ? wf : wb;
    int eo = e & 262143;
    int p = __builtin_amdgcn_cvt_pk_fp8_f32(src[eo] * 16.0f, src[eo + 1] * 16.0f, 0, false);
    out[i] = (unsigned short)(p & 0xFFFF);
  }
}

// ---------------- K1: fused char embed + char BiLSTM -> x[:,0:128] ---------
DEVI bf16x8 load_wfrag(const float* Wm, int rowbase, int l15, int lhi, int ks) {
  const float* p = Wm + (rowbase + l15) * 64 + ks * 32 + lhi * 8;
  u16x8 u;
  #pragma unroll
  for (int e = 0; e < 8; ++e) u[e] = f2bf(p[e]);
  return __builtin_bit_cast(bf16x8, u);
}

__launch_bounds__(256, 1)
__global__ void k_char_lstm(const int* chars, const float* cemb,
                            const float* cWih_f, const float* cWhh_f, const float* cb_f,
                            const float* cWih_b, const float* cWhh_b, const float* cb_b,
                            const float* h0c, const float* c0c,
                            unsigned short* x) {
  __shared__ unsigned short embT[128 * 64];
  __shared__ int charsT[16 * 64];
  __shared__ unsigned short hT[64 * 72];
  const int tid = threadIdx.x;
  const int w = tid >> 6, lane = tid & 63;
  const int l15 = lane & 15, lhi = lane >> 4;
  const int sbase = blockIdx.x * 64;

  for (int idx = tid; idx < 8192; idx += 256) embT[idx] = f2bf(cemb[idx]);
  for (int idx = tid; idx < 1024; idx += 256) {
    int s = idx >> 4, t = idx & 15;
    charsT[t * 64 + s] = chars[(sbase + s) * 16 + t];
  }
  for (int idx = tid; idx < 4096; idx += 256) {
    int s = idx >> 6, u = idx & 63;
    hT[s * 72 + u] = f2bf(h0c[(sbase + s) * 64 + u]);
  }
  bf16x8 bih[4][2], bhh[4][2];
  float bias[4];
  #pragma unroll
  for (int q = 0; q < 4; ++q) {
    bias[q] = cb_f[q * 64 + w * 16 + l15];
    #pragma unroll
    for (int ks = 0; ks < 2; ++ks) {
      bih[q][ks] = load_wfrag(cWih_f, (w + 4 * q) * 16, l15, lhi, ks);
      bhh[q][ks] = load_wfrag(cWhh_f, (w + 4 * q) * 16, l15, lhi, ks);
    }
  }
  float c_[4][4];
  #pragma unroll
  for (int mt = 0; mt < 4; ++mt)
    #pragma unroll
    for (int i = 0; i < 4; ++i)
      c_[mt][i] = c0c[(sbase + mt * 16 + lhi * 4 + i) * 64 + w * 16 + l15];
  float hfin[4][4];
  #pragma unroll
  for (int mt = 0; mt < 4; ++mt)
    #pragma unroll
    for (int i = 0; i < 4; ++i) hfin[mt][i] = 0.0f;
  __syncthreads();

  for (int t = 0; t < 16; ++t) {
    bf16x8 ax[4][2], ah[4][2];
    #pragma unroll
    for (int mt = 0; mt < 4; ++mt) {
      int cidx = charsT[t * 64 + mt * 16 + l15];
      #pragma unroll
      for (int ks = 0; ks < 2; ++ks) {
        ax[mt][ks] = __builtin_bit_cast(bf16x8, *(const u16x8*)&embT[cidx * 64 + ks * 32 + lhi * 8]);
        ah[mt][ks] = __builtin_bit_cast(bf16x8, *(const u16x8*)&hT[(mt * 16 + l15) * 72 + ks * 32 + lhi * 8]);
      }
    }
    f32x4 acc[4][4];
    #pragma unroll
    for (int mt = 0; mt < 4; ++mt)
      #pragma unroll
      for (int q = 0; q < 4; ++q) acc[mt][q] = (f32x4){0.f, 0.f, 0.f, 0.f};
    #pragma unroll
    for (int ks = 0; ks < 2; ++ks)
      #pragma unroll
      for (int mt = 0; mt < 4; ++mt)
        #pragma unroll
        for (int q = 0; q < 4; ++q) {
          acc[mt][q] = mfma_bf16(ax[mt][ks], bih[q][ks], acc[mt][q]);
          acc[mt][q] = mfma_bf16(ah[mt][ks], bhh[q][ks], acc[mt][q]);
        }
    __syncthreads();
    #pragma unroll
    for (int mt = 0; mt < 4; ++mt)
      #pragma unroll
      for (int i = 0; i < 4; ++i) {
        float gi = acc[mt][0][i] + bias[0];
        float gf = acc[mt][1][i] + bias[1];
        float gg = acc[mt][2][i] + bias[2];
        float go = acc[mt][3][i] + bias[3];
        float cn = sigf(gf) * c_[mt][i] + sigf(gi) * tanhf_(gg);
        float h = sigf(go) * tanhf_(cn);
        c_[mt][i] = cn;
        if (t == 15) hfin[mt][i] = h;
        hT[(mt * 16 + lhi * 4 + i) * 72 + w * 16 + l15] = f2bf(h);
      }
    __syncthreads();
  }
  #pragma unroll
  for (int mt = 0; mt < 4; ++mt)
    #pragma unroll
    for (int i = 0; i < 4; ++i) {
      int sg = sbase + mt * 16 + lhi * 4 + i;
      int xrow = (sg & 255) * 64 + (sg >> 8);
      x[xrow * 640 + w * 16 + l15] = f2bf(hfin[mt][i]);
    }
  #pragma unroll
  for (int q = 0; q < 4; ++q) {
    bias[q] = cb_b[q * 64 + w * 16 + l15];
    #pragma unroll
    for (int ks = 0; ks < 2; ++ks) {
      bih[q][ks] = load_wfrag(cWih_b, (w + 4 * q) * 16, l15, lhi, ks);
      bhh[q][ks] = load_wfrag(cWhh_b, (w + 4 * q) * 16, l15, lhi, ks);
    }
  }
  __syncthreads();
  for (int idx = tid; idx < 4096; idx += 256) {
    int s = idx >> 6, u = idx & 63;
    hT[s * 72 + u] = f2bf(h0c[16384 * 64 + (sbase + s) * 64 + u]);
  }
  __syncthreads();
  {
    bf16x8 ax[4][2], ah[4][2];
    #pragma unroll
    for (int mt = 0; mt < 4; ++mt) {
      int cidx = charsT[15 * 64 + mt * 16 + l15];
      #pragma unroll
      for (int ks = 0; ks < 2; ++ks) {
        ax[mt][ks] = __builtin_bit_cast(bf16x8, *(const u16x8*)&embT[cidx * 64 + ks * 32 + lhi * 8]);
        ah[mt][ks] = __builtin_bit_cast(bf16x8, *(const u16x8*)&hT[(mt * 16 + l15) * 72 + ks * 32 + lhi * 8]);
      }
    }
    f32x4 acc[4][4];
    #pragma unroll
    for (int mt = 0; mt < 4; ++mt)
      #pragma unroll
      for (int q = 0; q < 4; ++q) acc[mt][q] = (f32x4){0.f, 0.f, 0.f, 0.f};
    #pragma unroll
    for (int ks = 0; ks < 2; ++ks)
      #pragma unroll
      for (int mt = 0; mt < 4; ++mt)
        #pragma unroll
        for (int q = 0; q < 4; ++q) {
          acc[mt][q] = mfma_bf16(ax[mt][ks], bih[q][ks], acc[mt][q]);
          acc[mt][q] = mfma_bf16(ah[mt][ks], bhh[q][ks], acc[mt][q]);
        }
    #pragma unroll
    for (int mt = 0; mt < 4; ++mt)
      #pragma unroll
      for (int i = 0; i < 4; ++i) {
        float cc = c0c[16384 * 64 + (sbase + mt * 16 + lhi * 4 + i) * 64 + w * 16 + l15];
        float gi = acc[mt][0][i] + bias[0];
        float gf = acc[mt][1][i] + bias[1];
        float gg = acc[mt][2][i] + bias[2];
        float go = acc[mt][3][i] + bias[3];
        float cn = sigf(gf) * cc + sigf(gi) * tanhf_(gg);
        float h = sigf(go) * tanhf_(cn);
        int sg = sbase + mt * 16 + lhi * 4 + i;
        int xrow = (sg & 255) * 64 + (sg >> 8);
        x[xrow * 640 + 64 + w * 16 + l15] = f2bf(h);
      }
  }
}

// ---------------- K2: word-embed gather -> x[:,128:640] (bf16) -------------
__global__ void k_wembed(const int* sentence, const float* wemb, unsigned short* x) {
  int gid = blockIdx.x * 256 + threadIdx.x;
  int row = gid >> 6;
  int c8 = (gid & 63) * 8;
  int b = row & 63, t = row >> 6;
  int sent = sentence[b * 256 + t];
  const float* src = wemb + (long)sent * 512 + c8;
  u16x8 o;
  #pragma unroll
  for (int e = 0; e < 8; ++e) o[e] = f2bf(src[e]);
  *(u16x8*)&x[row * 640 + 128 + c8] = o;
}

// ---------------- K3: pre-gates GEMM  x[16384,640] @ wcat.T
// writes transposed pre2[rg][t][col 2048][8 rows] bf16
__launch_bounds__(256, 2)
__global__ void k_gemm_pre(const unsigned short* x, const unsigned short* wcat,
                           const float* wb_f, const float* wb_b,
                           unsigned short* pre2) {
  __shared__ __align__(16) unsigned char lds3[2][2][16384];
  const int tid = threadIdx.x;
  const int bm = blockIdx.x & 127, bn = blockIdx.x >> 7;
  const int m0 = bm * 128, n0 = bn * 128;
  const int lane = tid & 63, w = tid >> 6;
  const int l15 = lane & 15, lhi = lane >> 4;
  const int wm = (w & 1) * 64, wn = (w >> 1) * 64;

  u16x8 ra[4], rb[4];
  auto gload = [&](int kt) {
    #pragma unroll
    for (int i = 0; i < 4; ++i) {
      int o = tid * 16 + i * 4096;
      int r = o >> 7, cb = o & 127;
      ra[i] = *(const u16x8*)&x[(m0 + r) * 640 + kt * 64 + (cb >> 1)];
      rb[i] = *(const u16x8*)&wcat[(n0 + r) * 640 + kt * 64 + (cb >> 1)];
    }
  };
  auto swrite = [&](int buf) {
    #pragma unroll
    for (int i = 0; i < 4; ++i) {
      int o = tid * 16 + i * 4096;
      int osw = o ^ (((o >> 7) & 7) << 4);
      *(u16x8*)(&lds3[buf][0][0] + osw) = ra[i];
      *(u16x8*)(&lds3[buf][1][0] + osw) = rb[i];
    }
  };
  f32x4 acc[4][4];
  #pragma unroll
  for (int a = 0; a < 4; ++a)
    #pragma unroll
    for (int bb = 0; bb < 4; ++bb) acc[a][bb] = (f32x4){0.f, 0.f, 0.f, 0.f};

  gload(0); swrite(0); __syncthreads();
  for (int kt = 0; kt < 10; ++kt) {
    int cur = kt & 1;
    if (kt < 9) gload(kt + 1);
    #pragma unroll
    for (int ks = 0; ks < 2; ++ks) {
      bf16x8 af[4], bfv[4];
      #pragma unroll
      for (int mt = 0; mt < 4; ++mt) {
        int o = (wm + mt * 16 + l15) * 128 + ks * 64 + lhi * 16;
        o ^= ((o >> 7) & 7) << 4;
        af[mt] = __builtin_bit_cast(bf16x8, *(const u16x8*)(&lds3[cur][0][0] + o));
      }
      #pragma unroll
      for (int nt = 0; nt < 4; ++nt) {
        int o = (wn + nt * 16 + l15) * 128 + ks * 64 + lhi * 16;
        o ^= ((o >> 7) & 7) << 4;
        bfv[nt] = __builtin_bit_cast(bf16x8, *(const u16x8*)(&lds3[cur][1][0] + o));
      }
      #pragma unroll
      for (int mt = 0; mt < 4; ++mt)
        #pragma unroll
        for (int nt = 0; nt < 4; ++nt)
          acc[mt][nt] = mfma_bf16(af[mt], bfv[nt], acc[mt][nt]);
    }
    __syncthreads();
    if (kt < 9) { swrite(cur ^ 1); __syncthreads(); }
  }
  // epilogue: transposed store, 4 rows (=4 i) packed per 8B
  #pragma unroll
  for (int nt = 0; nt < 4; ++nt) {
    int col = n0 + wn + nt * 16 + l15;
    float bias = (col < 1024) ? wb_f[col] : wb_b[col - 1024];
    #pragma unroll
    for (int mt = 0; mt < 4; ++mt) {
      int row = m0 + wm + mt * 16 + lhi * 4;    // +i, i=0..3 consecutive
      int t = row >> 6, b = row & 63, rg = b >> 3, b8 = b & 7;
      u16x4 v;
      #pragma unroll
      for (int i = 0; i < 4; ++i) v[i] = f2bf(acc[mt][nt][i] + bias);
      *(u16x4*)&pre2[((long)(rg * 256 + t) * 2048 + col) * 8 + b8] = v;
    }
  }
}

// ---------------- K4: word LSTM recurrence v4 ------------------------------
// Same structure as v3, but the per-step barrier is LDS-only (s_waitcnt
// lgkmcnt(0) + s_barrier) so hout stores and pre2 prefetch loads stay in
// flight across steps instead of being drained by __syncthreads' vmcnt(0).
#define LSTM_STEP(SRC, DST, PU, TT)                                          \
  {                                                                          \
    long a8[8];                                                              \
    _Pragma("unroll")                                                        \
    for (int ks = 0; ks < 8; ++ks)                                           \
      a8[ks] = *(const long*)&SRC[l15 * 264 + ks * 32 + lhi * 8];            \
    f32x4 acc[4];                                                            \
    _Pragma("unroll")                                                        \
    for (int g = 0; g < 4; ++g) acc[g] = (f32x4){0.f, 0.f, 0.f, 0.f};        \
    _Pragma("unroll")                                                        \
    for (int ks = 0; ks < 8; ++ks)                                           \
      _Pragma("unroll")                                                      \
      for (int g = 0; g < 4; ++g)                                            \
        acc[g] = mfma_fp8(a8[ks], bfr[g][ks], acc[g]);                       \
    float ge[4][2];                                                          \
    _Pragma("unroll")                                                        \
    for (int g = 0; g < 4; ++g) {                                            \
      float s2 = __shfl_xor(acc[g][2], 32, 64);                              \
      float s3 = __shfl_xor(acc[g][3], 32, 64);                              \
      ge[g][0] = lowhalf ? acc[g][0] : s2;                                   \
      ge[g][1] = lowhalf ? acc[g][1] : s3;                                   \
    }                                                                        \
    _Pragma("unroll")                                                        \
    for (int j = 0; j < 2; ++j) {                                            \
      float gi = fmaf(ge[0][j], inv, bf2f(PU[0][j]));                        \
      float gf = fmaf(ge[1][j], inv, bf2f(PU[1][j]));                        \
      float gg = fmaf(ge[2][j], inv, bf2f(PU[2][j]));                        \
      float go = fmaf(ge[3][j], inv, bf2f(PU[3][j]));                        \
      float cn = sigf(gf) * c2[j] + sigf(gi) * tanhf_(gg);                   \
      float h = sigf(go) * tanhf_(cn);                                       \
      c2[j] = cn;                                                            \
      int p2 = __builtin_amdgcn_cvt_pk_fp8_f32(h * 16.0f, 0.0f, 0, false);   \
      DST[(rl0 + j) * 264 + uu] = (unsigned char)(p2 & 0xFF);                \
      hout[((long)(TT) * 64 + row0 + rl0 + j) * 512 + dco] = f2bf(h);        \
    }                                                                        \
  }

__launch_bounds__(1024, 4)
__global__ void k_word_lstm(const unsigned char* whh8, const unsigned short* pre2,
                            const float* h0w, const float* c0w,
                            unsigned short* hout) {
  __shared__ __align__(16) unsigned char hlds[2][16 * 264];   // fp8 h, x16 scale
  const int tid = threadIdx.x;
  const int w = tid >> 6, lane = tid & 63;
  const int l15 = lane & 15, lhi = lane >> 4;
  const int dir = blockIdx.x >> 3, rg = blockIdx.x & 7;
  const int row0 = rg * 8;
  const int uu = w * 16 + l15;
  const int dco = dir * 256 + uu;
  const bool lowhalf = (lhi < 2);
  // lane's 2 local rows: lhi 0->0,1  2->2,3  1->4,5  3->6,7
  const int rl0 = (lhi & 1) * 4 + (lhi >> 1) * 2;
  const unsigned char* W = whh8 + dir * 262144;

  long bfr[4][8];   // resident fp8 weights
  #pragma unroll
  for (int g = 0; g < 4; ++g) {
    int grow = g * 256 + uu;
    #pragma unroll
    for (int ks = 0; ks < 8; ++ks)
      bfr[g][ks] = *(const long*)(W + grow * 256 + ks * 32 + lhi * 8);
  }
  {   // init hlds[0] rows 0-7 from h0w; zero pad rows 8-15 in BOTH buffers
    int r = tid >> 6, u0 = (tid & 63) * 4;
    unsigned int pk = 0;
    if (r < 8) {
      const float* hp = h0w + dir * 16384 + (row0 + r) * 256 + u0;
      int pa = __builtin_amdgcn_cvt_pk_fp8_f32(hp[0] * 16.0f, hp[1] * 16.0f, 0, false);
      int pb = __builtin_amdgcn_cvt_pk_fp8_f32(hp[2] * 16.0f, hp[3] * 16.0f, 0, false);
      pk = (unsigned int)(pa & 0xFFFF) | ((unsigned int)(pb & 0xFFFF) << 16);
    }
    *(unsigned int*)&hlds[0][r * 264 + u0] = pk;
    if (r >= 8) *(unsigned int*)&hlds[1][r * 264 + u0] = 0;
  }
  float c2[2];
  #pragma unroll
  for (int j = 0; j < 2; ++j)
    c2[j] = c0w[dir * 16384 + (row0 + rl0 + j) * 256 + uu];

  // gate source base (element index into pre2)
  const unsigned short* pg0 = pre2 + ((long)rg * 256 * 2048 + dir * 1024 + uu) * 8 + rl0;

  u16x2 pA[4], pB[4];
  const int ttA0 = dir ? 255 : 0;
  #pragma unroll
  for (int g = 0; g < 4; ++g)
    pA[g] = *(const u16x2*)(pg0 + ttA0 * 16384 + g * 2048);
  __syncthreads();

  const float inv = 1.0f / 256.0f;
  for (int t = 0; t < 256; t += 2) {
    const int ttA = dir ? (255 - t) : t;
    const int ttB = dir ? (254 - t) : (t + 1);
    int ttC = dir ? (253 - t) : (t + 2);
    ttC = ttC < 0 ? 0 : (ttC > 255 ? 255 : ttC);
    // ---- step A: h in hlds[0] -> hlds[1], gates pA, prefetch pB(ttB) ----
    #pragma unroll
    for (int g = 0; g < 4; ++g)
      pB[g] = *(const u16x2*)(pg0 + ttB * 16384 + g * 2048);
    LSTM_STEP(hlds[0], hlds[1], pA, ttA)
    lds_barrier();
    // ---- step B: h in hlds[1] -> hlds[0], gates pB, prefetch pA(ttC) ----
    #pragma unroll
    for (int g = 0; g < 4; ++g)
      pA[g] = *(const u16x2*)(pg0 + ttC * 16384 + g * 2048);
    LSTM_STEP(hlds[1], hlds[0], pB, ttB)
    lds_barrier();
  }
}

// ---------------- K5: feats = h @ Wtag.T + btag  (N=12 padded to 16) -------
__launch_bounds__(256, 2)
__global__ void k_feats(const unsigned short* hbuf, const float* Wtag, const float* btag,
                        float* feats) {
  const int tid = threadIdx.x;
  const int w = tid >> 6, lane = tid & 63, l15 = lane & 15, lhi = lane >> 4;
  const int m0 = blockIdx.x * 64 + w * 16;
  bf16x8 bfr[16];
  #pragma unroll
  for (int ks = 0; ks < 16; ++ks) {
    u16x8 u;
    if (l15 < 12) {
      const float* p = Wtag + l15 * 512 + ks * 32 + lhi * 8;
      #pragma unroll
      for (int e = 0; e < 8; ++e) u[e] = f2bf(p[e]);
    } else {
      #pragma unroll
      for (int e = 0; e < 8; ++e) u[e] = 0;
    }
    bfr[ks] = __builtin_bit_cast(bf16x8, u);
  }
  f32x4 acc = {0.f, 0.f, 0.f, 0.f};
  #pragma unroll
  for (int ks = 0; ks < 16; ++ks) {
    u16x8 a = *(const u16x8*)&hbuf[(m0 + l15) * 512 + ks * 32 + lhi * 8];
    acc = mfma_bf16(__builtin_bit_cast(bf16x8, a), bfr[ks], acc);
  }
  float bias = (l15 < 12) ? btag[l15] : 0.0f;
  #pragma unroll
  for (int i = 0; i < 4; ++i)
    feats[(m0 + lhi * 4 + i) * 16 + l15] = acc[i] + bias;
}

// ---------------- K6: CRF forward + gold + loss ----------------------------
__launch_bounds__(1024, 1)
__global__ void k_crf(const float* feats, const float* trans, const int* tags, float* out) {
  __shared__ float alpha[2][64 * 16];
  __shared__ float red[1024];
  const int tid = threadIdx.x;
  const int j = tid & 15, b = tid >> 4;
  float tr[12];
  if (j < 12) {
    #pragma unroll
    for (int i = 0; i < 12; ++i) tr[i] = trans[j * 12 + i];
  }
  alpha[0][b * 16 + j] = (j == 0) ? 0.0f : -10000.0f;
  __syncthreads();
  int cur = 0;
  for (int t = 0; t < 256; ++t) {
    if (j < 12) {
      float s_[12], m = -3.4e38f;
      #pragma unroll
      for (int i = 0; i < 12; ++i) { s_[i] = alpha[cur][b * 16 + i] + tr[i]; m = fmaxf(m, s_[i]); }
      float sum = 0.f;
      #pragma unroll
      for (int i = 0; i < 12; ++i) sum += __expf(s_[i] - m);
      alpha[cur ^ 1][b * 16 + j] = m + __logf(sum) + feats[t * 1024 + b * 16 + j];
    }
    __syncthreads();
    cur ^= 1;
  }
  float part = 0.0f;
  if (tid < 64) {
    float s_[12], m = -3.4e38f;
    #pragma unroll
    for (int i = 0; i < 12; ++i) { s_[i] = alpha[cur][tid * 16 + i] + trans[2 * 12 + i]; m = fmaxf(m, s_[i]); }
    float sum = 0.f;
    #pragma unroll
    for (int i = 0; i < 12; ++i) sum += __expf(s_[i] - m);
    part = m + __logf(sum);
  }
  for (int idx = tid; idx < 16384; idx += 1024) {
    int t = idx >> 6, bb = idx & 63;
    int tg = tags[bb * 256 + t];
    int pv = (t == 0) ? 0 : tags[bb * 256 + t - 1];
    float g = feats[t * 1024 + bb * 16 + tg] + trans[tg * 12 + pv];
    if (t == 255) g += trans[2 * 12 + tg];
    part -= g;
  }
  red[tid] = part;
  __syncthreads();
  for (int st = 512; st > 0; st >>= 1) {
    if (tid < st) red[tid] += red[tid + st];
    __syncthreads();
  }
  if (tid == 0) out[0] = red[0] / 64.0f;
}

// ---------------------------------------------------------------------------
extern "C" void kernel_launch(void* const* d_in, const int* in_sizes, int n_in,
                              void* d_out, int out_size, void* d_ws, size_t ws_size,
                              hipStream_t stream) {
  const int*   sentence = (const int*)d_in[0];
  const int*   chars    = (const int*)d_in[1];
  const int*   tags     = (const int*)d_in[2];
  const float* wemb     = (const float*)d_in[3];
  const float* cemb     = (const float*)d_in[4];
  const float* cWih_f   = (const float*)d_in[5];
  const float* cWhh_f   = (const float*)d_in[6];
  const float* cb_f     = (const float*)d_in[7];
  const float* cWih_b   = (const float*)d_in[8];
  const float* cWhh_b   = (const float*)d_in[9];
  const float* cb_b     = (const float*)d_in[10];
  const float* wWih_f   = (const float*)d_in[11];
  const float* wWhh_f   = (const float*)d_in[12];
  const float* wb_f     = (const float*)d_in[13];
  const float* wWih_b   = (const float*)d_in[14];
  const float* wWhh_b   = (const float*)d_in[15];
  const float* wb_b     = (const float*)d_in[16];
  const float* Wtag     = (const float*)d_in[17];
  const float* btag     = (const float*)d_in[18];
  const float* trans    = (const float*)d_in[19];
  const float* h0c      = (const float*)d_in[20];
  const float* c0c      = (const float*)d_in[21];
  const float* h0w      = (const float*)d_in[22];
  const float* c0w      = (const float*)d_in[23];

  char* ws = (char*)d_ws;
  unsigned short* x     = (unsigned short*)(ws);
  unsigned short* pre2  = (unsigned short*)(ws + 20971520);
  unsigned short* hbuf  = (unsigned short*)(ws + 88080384);
  float*          feats = (float*)(ws + 104857600);
  unsigned short* wcat  = (unsigned short*)(ws + 105906176);
  unsigned char*  whh8  = (unsigned char*)(ws + 108527616);

  hipLaunchKernelGGL(k_cast_wih, dim3(5120), dim3(256), 0, stream, wWih_f, wWih_b, wcat);
  hipLaunchKernelGGL(k_cast_whh, dim3(1024), dim3(256), 0, stream, wWhh_f, wWhh_b, (unsigned short*)whh8);
  hipLaunchKernelGGL(k_char_lstm, dim3(256), dim3(256), 0, stream, chars, cemb,
                     cWih_f, cWhh_f, cb_f, cWih_b, cWhh_b, cb_b, h0c, c0c, x);
  hipLaunchKernelGGL(k_wembed, dim3(4096), dim3(256), 0, stream, sentence, wemb, x);
  hipLaunchKernelGGL(k_gemm_pre, dim3(2048), dim3(256), 0, stream, x, wcat, wb_f, wb_b, pre2);
  hipLaunchKernelGGL(k_word_lstm, dim3(16), dim3(1024), 0, stream, whh8, pre2, h0w, c0w, hbuf);
  hipLaunchKernelGGL(k_feats, dim3(256), dim3(256), 0, stream, hbuf, Wtag, btag, feats);
  hipLaunchKernelGGL(k_crf, dim3(1), dim3(1024), 0, stream, feats, trans, tags, (float*)d_out);
}

// Round 7
// 624.108 us; speedup vs baseline: 1.1264x; 1.1264x over previous
//
#include <hip/hip_runtime.h>

#define DEVI static __device__ __forceinline__

typedef __attribute__((ext_vector_type(4))) float f32x4;
typedef __attribute__((ext_vector_type(8))) __bf16 bf16x8;
typedef __attribute__((ext_vector_type(8))) unsigned short u16x8;
typedef __attribute__((ext_vector_type(4))) unsigned short u16x4;
typedef __attribute__((ext_vector_type(2))) unsigned short u16x2;
typedef __attribute__((ext_vector_type(8))) int i32x8;
typedef __attribute__((ext_vector_type(4))) long l64x4;

DEVI unsigned short f2bf(float f) {
  union { float f; unsigned int u; } v; v.f = f;
  unsigned int u = v.u;
  u += 0x7FFFu + ((u >> 16) & 1u);   // RNE
  return (unsigned short)(u >> 16);
}
DEVI float bf2f(unsigned short s) {
  union { unsigned int u; float f; } v; v.u = ((unsigned int)s) << 16;
  return v.f;
}
// branch-free fast sigmoid/tanh: 2 trans + 2-3 VALU each, correct saturation
DEVI float sigf(float x) {
  return __builtin_amdgcn_rcpf(1.0f + __builtin_amdgcn_exp2f(-1.44269504089f * x));
}
DEVI float tanhf_(float x) {
  return 1.0f - 2.0f * __builtin_amdgcn_rcpf(1.0f + __builtin_amdgcn_exp2f(2.88539008178f * x));
}
DEVI f32x4 mfma_bf16(bf16x8 a, bf16x8 b, f32x4 c) {
  return __builtin_amdgcn_mfma_f32_16x16x32_bf16(a, b, c, 0, 0, 0);
}
// MX-scaled fp8 MFMA K=128, scales=1.0 (E8M0 0x7F): 2x the non-scaled fp8 rate
DEVI f32x4 mfma_mx(i32x8 a, i32x8 b, f32x4 c) {
  return __builtin_amdgcn_mfma_scale_f32_16x16x128_f8f6f4(
      a, b, c, 0 /*fp8*/, 0 /*fp8*/, 0, 0x7F7F7F7F, 0, 0x7F7F7F7F);
}
// LDS-only barrier: does NOT drain vmcnt.
DEVI void lds_barrier() {
  asm volatile("s_waitcnt lgkmcnt(0)" ::: "memory");
  __builtin_amdgcn_s_barrier();
}

// ---------------- K0a: wWih_{f,b} f32 -> bf16, concat rows [2048][640] ----
__global__ void k_cast_wih(const float* wf, const float* wb, unsigned short* out) {
  int i = blockIdx.x * 256 + threadIdx.x;   // 2048*640 = 1,310,720
  if (i < 2048 * 640) {
    int r = i / 640, c = i - r * 640;
    float v = (r < 1024) ? wf[r * 640 + c] : wb[(r - 1024) * 640 + c];
    out[i] = f2bf(v);
  }
}

// ---------------- K0b: wWhh_{f,b} f32 -> fp8 e4m3 (x16 scale) [2][1024][256]
__global__ void k_cast_whh(const float* wf, const float* wb, unsigned short* out) {
  int i = blockIdx.x * 256 + threadIdx.x;   // pairs: 524288/2 = 262144
  if (i < 262144) {
    int e = i * 2;
    const float* src = (e < 262144) ? wf : wb;
    int eo = e & 262143;
    int p = __builtin_amdgcn_cvt_pk_fp8_f32(src[eo] * 16.0f, src[eo + 1] * 16.0f, 0, false);
    out[i] = (unsigned short)(p & 0xFFFF);
  }
}

// ---------------- K1: fused char embed + char BiLSTM -> x[:,0:128] ---------
DEVI bf16x8 load_wfrag(const float* Wm, int rowbase, int l15, int lhi, int ks) {
  const float* p = Wm + (rowbase + l15) * 64 + ks * 32 + lhi * 8;
  u16x8 u;
  #pragma unroll
  for (int e = 0; e < 8; ++e) u[e] = f2bf(p[e]);
  return __builtin_bit_cast(bf16x8, u);
}

__launch_bounds__(256, 1)
__global__ void k_char_lstm(const int* chars, const float* cemb,
                            const float* cWih_f, const float* cWhh_f, const float* cb_f,
                            const float* cWih_b, const float* cWhh_b, const float* cb_b,
                            const float* h0c, const float* c0c,
                            unsigned short* x) {
  __shared__ unsigned short embT[128 * 64];
  __shared__ int charsT[16 * 64];
  __shared__ unsigned short hT[64 * 72];
  const int tid = threadIdx.x;
  const int w = tid >> 6, lane = tid & 63;
  const int l15 = lane & 15, lhi = lane >> 4;
  const int sbase = blockIdx.x * 64;

  for (int idx = tid; idx < 8192; idx += 256) embT[idx] = f2bf(cemb[idx]);
  for (int idx = tid; idx < 1024; idx += 256) {
    int s = idx >> 4, t = idx & 15;
    charsT[t * 64 + s] = chars[(sbase + s) * 16 + t];
  }
  for (int idx = tid; idx < 4096; idx += 256) {
    int s = idx >> 6, u = idx & 63;
    hT[s * 72 + u] = f2bf(h0c[(sbase + s) * 64 + u]);
  }
  bf16x8 bih[4][2], bhh[4][2];
  float bias[4];
  #pragma unroll
  for (int q = 0; q < 4; ++q) {
    bias[q] = cb_f[q * 64 + w * 16 + l15];
    #pragma unroll
    for (int ks = 0; ks < 2; ++ks) {
      bih[q][ks] = load_wfrag(cWih_f, (w + 4 * q) * 16, l15, lhi, ks);
      bhh[q][ks] = load_wfrag(cWhh_f, (w + 4 * q) * 16, l15, lhi, ks);
    }
  }
  float c_[4][4];
  #pragma unroll
  for (int mt = 0; mt < 4; ++mt)
    #pragma unroll
    for (int i = 0; i < 4; ++i)
      c_[mt][i] = c0c[(sbase + mt * 16 + lhi * 4 + i) * 64 + w * 16 + l15];
  float hfin[4][4];
  #pragma unroll
  for (int mt = 0; mt < 4; ++mt)
    #pragma unroll
    for (int i = 0; i < 4; ++i) hfin[mt][i] = 0.0f;
  __syncthreads();

  for (int t = 0; t < 16; ++t) {
    bf16x8 ax[4][2], ah[4][2];
    #pragma unroll
    for (int mt = 0; mt < 4; ++mt) {
      int cidx = charsT[t * 64 + mt * 16 + l15];
      #pragma unroll
      for (int ks = 0; ks < 2; ++ks) {
        ax[mt][ks] = __builtin_bit_cast(bf16x8, *(const u16x8*)&embT[cidx * 64 + ks * 32 + lhi * 8]);
        ah[mt][ks] = __builtin_bit_cast(bf16x8, *(const u16x8*)&hT[(mt * 16 + l15) * 72 + ks * 32 + lhi * 8]);
      }
    }
    f32x4 acc[4][4];
    #pragma unroll
    for (int mt = 0; mt < 4; ++mt)
      #pragma unroll
      for (int q = 0; q < 4; ++q) acc[mt][q] = (f32x4){0.f, 0.f, 0.f, 0.f};
    #pragma unroll
    for (int ks = 0; ks < 2; ++ks)
      #pragma unroll
      for (int mt = 0; mt < 4; ++mt)
        #pragma unroll
        for (int q = 0; q < 4; ++q) {
          acc[mt][q] = mfma_bf16(ax[mt][ks], bih[q][ks], acc[mt][q]);
          acc[mt][q] = mfma_bf16(ah[mt][ks], bhh[q][ks], acc[mt][q]);
        }
    __syncthreads();
    #pragma unroll
    for (int mt = 0; mt < 4; ++mt)
      #pragma unroll
      for (int i = 0; i < 4; ++i) {
        float gi = acc[mt][0][i] + bias[0];
        float gf = acc[mt][1][i] + bias[1];
        float gg = acc[mt][2][i] + bias[2];
        float go = acc[mt][3][i] + bias[3];
        float cn = sigf(gf) * c_[mt][i] + sigf(gi) * tanhf_(gg);
        float h = sigf(go) * tanhf_(cn);
        c_[mt][i] = cn;
        if (t == 15) hfin[mt][i] = h;
        hT[(mt * 16 + lhi * 4 + i) * 72 + w * 16 + l15] = f2bf(h);
      }
    __syncthreads();
  }
  #pragma unroll
  for (int mt = 0; mt < 4; ++mt)
    #pragma unroll
    for (int i = 0; i < 4; ++i) {
      int sg = sbase + mt * 16 + lhi * 4 + i;
      int xrow = (sg & 255) * 64 + (sg >> 8);
      x[xrow * 640 + w * 16 + l15] = f2bf(hfin[mt][i]);
    }
  #pragma unroll
  for (int q = 0; q < 4; ++q) {
    bias[q] = cb_b[q * 64 + w * 16 + l15];
    #pragma unroll
    for (int ks = 0; ks < 2; ++ks) {
      bih[q][ks] = load_wfrag(cWih_b, (w + 4 * q) * 16, l15, lhi, ks);
      bhh[q][ks] = load_wfrag(cWhh_b, (w + 4 * q) * 16, l15, lhi, ks);
    }
  }
  __syncthreads();
  for (int idx = tid; idx < 4096; idx += 256) {
    int s = idx >> 6, u = idx & 63;
    hT[s * 72 + u] = f2bf(h0c[16384 * 64 + (sbase + s) * 64 + u]);
  }
  __syncthreads();
  {
    bf16x8 ax[4][2], ah[4][2];
    #pragma unroll
    for (int mt = 0; mt < 4; ++mt) {
      int cidx = charsT[15 * 64 + mt * 16 + l15];
      #pragma unroll
      for (int ks = 0; ks < 2; ++ks) {
        ax[mt][ks] = __builtin_bit_cast(bf16x8, *(const u16x8*)&embT[cidx * 64 + ks * 32 + lhi * 8]);
        ah[mt][ks] = __builtin_bit_cast(bf16x8, *(const u16x8*)&hT[(mt * 16 + l15) * 72 + ks * 32 + lhi * 8]);
      }
    }
    f32x4 acc[4][4];
    #pragma unroll
    for (int mt = 0; mt < 4; ++mt)
      #pragma unroll
      for (int q = 0; q < 4; ++q) acc[mt][q] = (f32x4){0.f, 0.f, 0.f, 0.f};
    #pragma unroll
    for (int ks = 0; ks < 2; ++ks)
      #pragma unroll
      for (int mt = 0; mt < 4; ++mt)
        #pragma unroll
        for (int q = 0; q < 4; ++q) {
          acc[mt][q] = mfma_bf16(ax[mt][ks], bih[q][ks], acc[mt][q]);
          acc[mt][q] = mfma_bf16(ah[mt][ks], bhh[q][ks], acc[mt][q]);
        }
    #pragma unroll
    for (int mt = 0; mt < 4; ++mt)
      #pragma unroll
      for (int i = 0; i < 4; ++i) {
        float cc = c0c[16384 * 64 + (sbase + mt * 16 + lhi * 4 + i) * 64 + w * 16 + l15];
        float gi = acc[mt][0][i] + bias[0];
        float gf = acc[mt][1][i] + bias[1];
        float gg = acc[mt][2][i] + bias[2];
        float go = acc[mt][3][i] + bias[3];
        float cn = sigf(gf) * cc + sigf(gi) * tanhf_(gg);
        float h = sigf(go) * tanhf_(cn);
        int sg = sbase + mt * 16 + lhi * 4 + i;
        int xrow = (sg & 255) * 64 + (sg >> 8);
        x[xrow * 640 + 64 + w * 16 + l15] = f2bf(h);
      }
  }
}

// ---------------- K2: word-embed gather -> x[:,128:640] (bf16) -------------
__global__ void k_wembed(const int* sentence, const float* wemb, unsigned short* x) {
  int gid = blockIdx.x * 256 + threadIdx.x;
  int row = gid >> 6;
  int c8 = (gid & 63) * 8;
  int b = row & 63, t = row >> 6;
  int sent = sentence[b * 256 + t];
  const float* src = wemb + (long)sent * 512 + c8;
  u16x8 o;
  #pragma unroll
  for (int e = 0; e < 8; ++e) o[e] = f2bf(src[e]);
  *(u16x8*)&x[row * 640 + 128 + c8] = o;
}

// ---------------- K3: pre-gates GEMM  x[16384,640] @ wcat.T
// writes transposed pre2[rg][t][col 2048][8 rows] bf16
__launch_bounds__(256, 2)
__global__ void k_gemm_pre(const unsigned short* x, const unsigned short* wcat,
                           const float* wb_f, const float* wb_b,
                           unsigned short* pre2) {
  __shared__ __align__(16) unsigned char lds3[2][2][16384];
  const int tid = threadIdx.x;
  const int bm = blockIdx.x & 127, bn = blockIdx.x >> 7;
  const int m0 = bm * 128, n0 = bn * 128;
  const int lane = tid & 63, w = tid >> 6;
  const int l15 = lane & 15, lhi = lane >> 4;
  const int wm = (w & 1) * 64, wn = (w >> 1) * 64;

  u16x8 ra[4], rb[4];
  auto gload = [&](int kt) {
    #pragma unroll
    for (int i = 0; i < 4; ++i) {
      int o = tid * 16 + i * 4096;
      int r = o >> 7, cb = o & 127;
      ra[i] = *(const u16x8*)&x[(m0 + r) * 640 + kt * 64 + (cb >> 1)];
      rb[i] = *(const u16x8*)&wcat[(n0 + r) * 640 + kt * 64 + (cb >> 1)];
    }
  };
  auto swrite = [&](int buf) {
    #pragma unroll
    for (int i = 0; i < 4; ++i) {
      int o = tid * 16 + i * 4096;
      int osw = o ^ (((o >> 7) & 7) << 4);
      *(u16x8*)(&lds3[buf][0][0] + osw) = ra[i];
      *(u16x8*)(&lds3[buf][1][0] + osw) = rb[i];
    }
  };
  f32x4 acc[4][4];
  #pragma unroll
  for (int a = 0; a < 4; ++a)
    #pragma unroll
    for (int bb = 0; bb < 4; ++bb) acc[a][bb] = (f32x4){0.f, 0.f, 0.f, 0.f};

  gload(0); swrite(0); __syncthreads();
  for (int kt = 0; kt < 10; ++kt) {
    int cur = kt & 1;
    if (kt < 9) gload(kt + 1);
    #pragma unroll
    for (int ks = 0; ks < 2; ++ks) {
      bf16x8 af[4], bfv[4];
      #pragma unroll
      for (int mt = 0; mt < 4; ++mt) {
        int o = (wm + mt * 16 + l15) * 128 + ks * 64 + lhi * 16;
        o ^= ((o >> 7) & 7) << 4;
        af[mt] = __builtin_bit_cast(bf16x8, *(const u16x8*)(&lds3[cur][0][0] + o));
      }
      #pragma unroll
      for (int nt = 0; nt < 4; ++nt) {
        int o = (wn + nt * 16 + l15) * 128 + ks * 64 + lhi * 16;
        o ^= ((o >> 7) & 7) << 4;
        bfv[nt] = __builtin_bit_cast(bf16x8, *(const u16x8*)(&lds3[cur][1][0] + o));
      }
      #pragma unroll
      for (int mt = 0; mt < 4; ++mt)
        #pragma unroll
        for (int nt = 0; nt < 4; ++nt)
          acc[mt][nt] = mfma_bf16(af[mt], bfv[nt], acc[mt][nt]);
    }
    __syncthreads();
    if (kt < 9) { swrite(cur ^ 1); __syncthreads(); }
  }
  // epilogue: transposed store, 4 rows (=4 i) packed per 8B
  #pragma unroll
  for (int nt = 0; nt < 4; ++nt) {
    int col = n0 + wn + nt * 16 + l15;
    float bias = (col < 1024) ? wb_f[col] : wb_b[col - 1024];
    #pragma unroll
    for (int mt = 0; mt < 4; ++mt) {
      int row = m0 + wm + mt * 16 + lhi * 4;    // +i, i=0..3 consecutive
      int t = row >> 6, b = row & 63, rg = b >> 3, b8 = b & 7;
      u16x4 v;
      #pragma unroll
      for (int i = 0; i < 4; ++i) v[i] = f2bf(acc[mt][nt][i] + bias);
      *(u16x4*)&pre2[((long)(rg * 256 + t) * 2048 + col) * 8 + b8] = v;
    }
  }
}

// ---------------- K4: word LSTM recurrence v5 (MX fp8 K=128) ---------------
// Same structure as v4, MFMA switched to mfma_scale 16x16x128 fp8 with
// scales=1.0: 8 MFMA/wave/step instead of 32, 2x pipe rate. A/B use the
// same k-byte-permutation (chunks ks*32+lhi*8) so the contraction is exact.
#define LSTM_STEP(SRC, DST, PU, TT)                                          \
  {                                                                          \
    long a8[8];                                                              \
    _Pragma("unroll")                                                        \
    for (int ks = 0; ks < 8; ++ks)                                           \
      a8[ks] = *(const long*)&SRC[l15 * 264 + ks * 32 + lhi * 8];            \
    l64x4 alo4 = {a8[0], a8[1], a8[2], a8[3]};                               \
    l64x4 ahi4 = {a8[4], a8[5], a8[6], a8[7]};                               \
    i32x8 aLo = __builtin_bit_cast(i32x8, alo4);                             \
    i32x8 aHi = __builtin_bit_cast(i32x8, ahi4);                             \
    f32x4 acc[4];                                                            \
    _Pragma("unroll")                                                        \
    for (int g = 0; g < 4; ++g) acc[g] = (f32x4){0.f, 0.f, 0.f, 0.f};        \
    _Pragma("unroll")                                                        \
    for (int g = 0; g < 4; ++g) {                                            \
      acc[g] = mfma_mx(aLo, bfr2[g][0], acc[g]);                             \
      acc[g] = mfma_mx(aHi, bfr2[g][1], acc[g]);                             \
    }                                                                        \
    float ge[4][2];                                                          \
    _Pragma("unroll")                                                        \
    for (int g = 0; g < 4; ++g) {                                            \
      float s2 = __shfl_xor(acc[g][2], 32, 64);                              \
      float s3 = __shfl_xor(acc[g][3], 32, 64);                              \
      ge[g][0] = lowhalf ? acc[g][0] : s2;                                   \
      ge[g][1] = lowhalf ? acc[g][1] : s3;                                   \
    }                                                                        \
    _Pragma("unroll")                                                        \
    for (int j = 0; j < 2; ++j) {                                            \
      float gi = fmaf(ge[0][j], inv, bf2f(PU[0][j]));                        \
      float gf = fmaf(ge[1][j], inv, bf2f(PU[1][j]));                        \
      float gg = fmaf(ge[2][j], inv, bf2f(PU[2][j]));                        \
      float go = fmaf(ge[3][j], inv, bf2f(PU[3][j]));                        \
      float cn = sigf(gf) * c2[j] + sigf(gi) * tanhf_(gg);                   \
      float h = sigf(go) * tanhf_(cn);                                       \
      c2[j] = cn;                                                            \
      int p2 = __builtin_amdgcn_cvt_pk_fp8_f32(h * 16.0f, 0.0f, 0, false);   \
      DST[(rl0 + j) * 264 + uu] = (unsigned char)(p2 & 0xFF);                \
      hout[((long)(TT) * 64 + row0 + rl0 + j) * 512 + dco] = f2bf(h);        \
    }                                                                        \
  }

__launch_bounds__(1024, 4)
__global__ void k_word_lstm(const unsigned char* whh8, const unsigned short* pre2,
                            const float* h0w, const float* c0w,
                            unsigned short* hout) {
  __shared__ __align__(16) unsigned char hlds[2][16 * 264];   // fp8 h, x16 scale
  const int tid = threadIdx.x;
  const int w = tid >> 6, lane = tid & 63;
  const int l15 = lane & 15, lhi = lane >> 4;
  const int dir = blockIdx.x >> 3, rg = blockIdx.x & 7;
  const int row0 = rg * 8;
  const int uu = w * 16 + l15;
  const int dco = dir * 256 + uu;
  const bool lowhalf = (lhi < 2);
  // lane's 2 local rows: lhi 0->0,1  2->2,3  1->4,5  3->6,7
  const int rl0 = (lhi & 1) * 4 + (lhi >> 1) * 2;
  const unsigned char* W = whh8 + dir * 262144;

  i32x8 bfr2[4][2];   // resident fp8 weights, repacked for K=128 MFMA
  #pragma unroll
  for (int g = 0; g < 4; ++g) {
    int grow = g * 256 + uu;
    #pragma unroll
    for (int kt = 0; kt < 2; ++kt) {
      long t0 = *(const long*)(W + grow * 256 + (kt * 4 + 0) * 32 + lhi * 8);
      long t1 = *(const long*)(W + grow * 256 + (kt * 4 + 1) * 32 + lhi * 8);
      long t2 = *(const long*)(W + grow * 256 + (kt * 4 + 2) * 32 + lhi * 8);
      long t3 = *(const long*)(W + grow * 256 + (kt * 4 + 3) * 32 + lhi * 8);
      l64x4 v = {t0, t1, t2, t3};
      bfr2[g][kt] = __builtin_bit_cast(i32x8, v);
    }
  }
  {   // init hlds[0] rows 0-7 from h0w; zero pad rows 8-15 in BOTH buffers
    int r = tid >> 6, u0 = (tid & 63) * 4;
    unsigned int pk = 0;
    if (r < 8) {
      const float* hp = h0w + dir * 16384 + (row0 + r) * 256 + u0;
      int pa = __builtin_amdgcn_cvt_pk_fp8_f32(hp[0] * 16.0f, hp[1] * 16.0f, 0, false);
      int pb = __builtin_amdgcn_cvt_pk_fp8_f32(hp[2] * 16.0f, hp[3] * 16.0f, 0, false);
      pk = (unsigned int)(pa & 0xFFFF) | ((unsigned int)(pb & 0xFFFF) << 16);
    }
    *(unsigned int*)&hlds[0][r * 264 + u0] = pk;
    if (r >= 8) *(unsigned int*)&hlds[1][r * 264 + u0] = 0;
  }
  float c2[2];
  #pragma unroll
  for (int j = 0; j < 2; ++j)
    c2[j] = c0w[dir * 16384 + (row0 + rl0 + j) * 256 + uu];

  // gate source base (element index into pre2)
  const unsigned short* pg0 = pre2 + ((long)rg * 256 * 2048 + dir * 1024 + uu) * 8 + rl0;

  u16x2 pA[4], pB[4];
  const int ttA0 = dir ? 255 : 0;
  #pragma unroll
  for (int g = 0; g < 4; ++g)
    pA[g] = *(const u16x2*)(pg0 + ttA0 * 16384 + g * 2048);
  __syncthreads();

  const float inv = 1.0f / 256.0f;
  for (int t = 0; t < 256; t += 2) {
    const int ttA = dir ? (255 - t) : t;
    const int ttB = dir ? (254 - t) : (t + 1);
    int ttC = dir ? (253 - t) : (t + 2);
    ttC = ttC < 0 ? 0 : (ttC > 255 ? 255 : ttC);
    // ---- step A: h in hlds[0] -> hlds[1], gates pA, prefetch pB(ttB) ----
    #pragma unroll
    for (int g = 0; g < 4; ++g)
      pB[g] = *(const u16x2*)(pg0 + ttB * 16384 + g * 2048);
    LSTM_STEP(hlds[0], hlds[1], pA, ttA)
    lds_barrier();
    // ---- step B: h in hlds[1] -> hlds[0], gates pB, prefetch pA(ttC) ----
    #pragma unroll
    for (int g = 0; g < 4; ++g)
      pA[g] = *(const u16x2*)(pg0 + ttC * 16384 + g * 2048);
    LSTM_STEP(hlds[1], hlds[0], pB, ttB)
    lds_barrier();
  }
}

// ---------------- K5: feats = h @ Wtag.T + btag  (N=12 padded to 16) -------
__launch_bounds__(256, 2)
__global__ void k_feats(const unsigned short* hbuf, const float* Wtag, const float* btag,
                        float* feats) {
  const int tid = threadIdx.x;
  const int w = tid >> 6, lane = tid & 63, l15 = lane & 15, lhi = lane >> 4;
  const int m0 = blockIdx.x * 64 + w * 16;
  bf16x8 bfr[16];
  #pragma unroll
  for (int ks = 0; ks < 16; ++ks) {
    u16x8 u;
    if (l15 < 12) {
      const float* p = Wtag + l15 * 512 + ks * 32 + lhi * 8;
      #pragma unroll
      for (int e = 0; e < 8; ++e) u[e] = f2bf(p[e]);
    } else {
      #pragma unroll
      for (int e = 0; e < 8; ++e) u[e] = 0;
    }
    bfr[ks] = __builtin_bit_cast(bf16x8, u);
  }
  f32x4 acc = {0.f, 0.f, 0.f, 0.f};
  #pragma unroll
  for (int ks = 0; ks < 16; ++ks) {
    u16x8 a = *(const u16x8*)&hbuf[(m0 + l15) * 512 + ks * 32 + lhi * 8];
    acc = mfma_bf16(__builtin_bit_cast(bf16x8, a), bfr[ks], acc);
  }
  float bias = (l15 < 12) ? btag[l15] : 0.0f;
  #pragma unroll
  for (int i = 0; i < 4; ++i)
    feats[(m0 + lhi * 4 + i) * 16 + l15] = acc[i] + bias;
}

// ---------------- K6: CRF forward + gold + loss ----------------------------
__launch_bounds__(1024, 1)
__global__ void k_crf(const float* feats, const float* trans, const int* tags, float* out) {
  __shared__ float alpha[2][64 * 16];
  __shared__ float red[1024];
  const int tid = threadIdx.x;
  const int j = tid & 15, b = tid >> 4;
  float tr[12];
  if (j < 12) {
    #pragma unroll
    for (int i = 0; i < 12; ++i) tr[i] = trans[j * 12 + i];
  }
  alpha[0][b * 16 + j] = (j == 0) ? 0.0f : -10000.0f;
  __syncthreads();
  int cur = 0;
  for (int t = 0; t < 256; ++t) {
    if (j < 12) {
      float s_[12], m = -3.4e38f;
      #pragma unroll
      for (int i = 0; i < 12; ++i) { s_[i] = alpha[cur][b * 16 + i] + tr[i]; m = fmaxf(m, s_[i]); }
      float sum = 0.f;
      #pragma unroll
      for (int i = 0; i < 12; ++i) sum += __expf(s_[i] - m);
      alpha[cur ^ 1][b * 16 + j] = m + __logf(sum) + feats[t * 1024 + b * 16 + j];
    }
    __syncthreads();
    cur ^= 1;
  }
  float part = 0.0f;
  if (tid < 64) {
    float s_[12], m = -3.4e38f;
    #pragma unroll
    for (int i = 0; i < 12; ++i) { s_[i] = alpha[cur][tid * 16 + i] + trans[2 * 12 + i]; m = fmaxf(m, s_[i]); }
    float sum = 0.f;
    #pragma unroll
    for (int i = 0; i < 12; ++i) sum += __expf(s_[i] - m);
    part = m + __logf(sum);
  }
  for (int idx = tid; idx < 16384; idx += 1024) {
    int t = idx >> 6, bb = idx & 63;
    int tg = tags[bb * 256 + t];
    int pv = (t == 0) ? 0 : tags[bb * 256 + t - 1];
    float g = feats[t * 1024 + bb * 16 + tg] + trans[tg * 12 + pv];
    if (t == 255) g += trans[2 * 12 + tg];
    part -= g;
  }
  red[tid] = part;
  __syncthreads();
  for (int st = 512; st > 0; st >>= 1) {
    if (tid < st) red[tid] += red[tid + st];
    __syncthreads();
  }
  if (tid == 0) out[0] = red[0] / 64.0f;
}

// ---------------------------------------------------------------------------
extern "C" void kernel_launch(void* const* d_in, const int* in_sizes, int n_in,
                              void* d_out, int out_size, void* d_ws, size_t ws_size,
                              hipStream_t stream) {
  const int*   sentence = (const int*)d_in[0];
  const int*   chars    = (const int*)d_in[1];
  const int*   tags     = (const int*)d_in[2];
  const float* wemb     = (const float*)d_in[3];
  const float* cemb     = (const float*)d_in[4];
  const float* cWih_f   = (const float*)d_in[5];
  const float* cWhh_f   = (const float*)d_in[6];
  const float* cb_f     = (const float*)d_in[7];
  const float* cWih_b   = (const float*)d_in[8];
  const float* cWhh_b   = (const float*)d_in[9];
  const float* cb_b     = (const float*)d_in[10];
  const float* wWih_f   = (const float*)d_in[11];
  const float* wWhh_f   = (const float*)d_in[12];
  const float* wb_f     = (const float*)d_in[13];
  const float* wWih_b   = (const float*)d_in[14];
  const float* wWhh_b   = (const float*)d_in[15];
  const float* wb_b     = (const float*)d_in[16];
  const float* Wtag     = (const float*)d_in[17];
  const float* btag     = (const float*)d_in[18];
  const float* trans    = (const float*)d_in[19];
  const float* h0c      = (const float*)d_in[20];
  const float* c0c      = (const float*)d_in[21];
  const float* h0w      = (const float*)d_in[22];
  const float* c0w      = (const float*)d_in[23];

  char* ws = (char*)d_ws;
  unsigned short* x     = (unsigned short*)(ws);
  unsigned short* pre2  = (unsigned short*)(ws + 20971520);
  unsigned short* hbuf  = (unsigned short*)(ws + 88080384);
  float*          feats = (float*)(ws + 104857600);
  unsigned short* wcat  = (unsigned short*)(ws + 105906176);
  unsigned char*  whh8  = (unsigned char*)(ws + 108527616);

  hipLaunchKernelGGL(k_cast_wih, dim3(5120), dim3(256), 0, stream, wWih_f, wWih_b, wcat);
  hipLaunchKernelGGL(k_cast_whh, dim3(1024), dim3(256), 0, stream, wWhh_f, wWhh_b, (unsigned short*)whh8);
  hipLaunchKernelGGL(k_char_lstm, dim3(256), dim3(256), 0, stream, chars, cemb,
                     cWih_f, cWhh_f, cb_f, cWih_b, cWhh_b, cb_b, h0c, c0c, x);
  hipLaunchKernelGGL(k_wembed, dim3(4096), dim3(256), 0, stream, sentence, wemb, x);
  hipLaunchKernelGGL(k_gemm_pre, dim3(2048), dim3(256), 0, stream, x, wcat, wb_f, wb_b, pre2);
  hipLaunchKernelGGL(k_word_lstm, dim3(16), dim3(1024), 0, stream, whh8, pre2, h0w, c0w, hbuf);
  hipLaunchKernelGGL(k_feats, dim3(256), dim3(256), 0, stream, hbuf, Wtag, btag, feats);
  hipLaunchKernelGGL(k_crf, dim3(1), dim3(1024), 0, stream, feats, trans, tags, (float*)d_out);
}

// Round 8
// 562.960 us; speedup vs baseline: 1.2487x; 1.1086x over previous
//
#include <hip/hip_runtime.h>

#define DEVI static __device__ __forceinline__

typedef __attribute__((ext_vector_type(4))) float f32x4;
typedef __attribute__((ext_vector_type(8))) __bf16 bf16x8;
typedef __attribute__((ext_vector_type(8))) unsigned short u16x8;
typedef __attribute__((ext_vector_type(4))) unsigned short u16x4;
typedef __attribute__((ext_vector_type(8))) int i32x8;
typedef __attribute__((ext_vector_type(4))) long l64x4;

DEVI unsigned short f2bf(float f) {
  union { float f; unsigned int u; } v; v.f = f;
  unsigned int u = v.u;
  u += 0x7FFFu + ((u >> 16) & 1u);   // RNE
  return (unsigned short)(u >> 16);
}
DEVI float bf2f(unsigned short s) {
  union { unsigned int u; float f; } v; v.u = ((unsigned int)s) << 16;
  return v.f;
}
// branch-free fast sigmoid/tanh: 2 trans + 2-3 VALU each, correct saturation
DEVI float sigf(float x) {
  return __builtin_amdgcn_rcpf(1.0f + __builtin_amdgcn_exp2f(-1.44269504089f * x));
}
DEVI float tanhf_(float x) {
  return 1.0f - 2.0f * __builtin_amdgcn_rcpf(1.0f + __builtin_amdgcn_exp2f(2.88539008178f * x));
}
DEVI f32x4 mfma_bf16(bf16x8 a, bf16x8 b, f32x4 c) {
  return __builtin_amdgcn_mfma_f32_16x16x32_bf16(a, b, c, 0, 0, 0);
}
// MX-scaled fp8 MFMA K=128, scales=1.0 (E8M0 0x7F): 2x the non-scaled fp8 rate
DEVI f32x4 mfma_mx(i32x8 a, i32x8 b, f32x4 c) {
  return __builtin_amdgcn_mfma_scale_f32_16x16x128_f8f6f4(
      a, b, c, 0 /*fp8*/, 0 /*fp8*/, 0, 0x7F7F7F7F, 0, 0x7F7F7F7F);
}
// LDS-only barrier: does NOT drain vmcnt.
DEVI void lds_barrier() {
  asm volatile("s_waitcnt lgkmcnt(0)" ::: "memory");
  __builtin_amdgcn_s_barrier();
}

// ---------------- K0: merged prep: cast wWih->bf16, wWhh->fp8, wembed gather
__global__ void k_prep(const float* wih_f, const float* wih_b,
                       const float* whh_f, const float* whh_b,
                       const int* sentence, const float* wemb,
                       unsigned short* wcat, unsigned short* whh8,
                       unsigned short* x) {
  int bid = blockIdx.x;
  if (bid < 5120) {                       // wWih cast: 2048x640 bf16
    int i = bid * 256 + threadIdx.x;
    int r = i / 640, c = i - r * 640;
    float v = (r < 1024) ? wih_f[r * 640 + c] : wih_b[(r - 1024) * 640 + c];
    wcat[i] = f2bf(v);
  } else if (bid < 6144) {                // wWhh cast: fp8 x16, 262144 pairs
    int i = (bid - 5120) * 256 + threadIdx.x;
    int e = i * 2;
    const float* src = (e < 262144) ? whh_f : whh_b;
    int eo = e & 262143;
    int p = __builtin_amdgcn_cvt_pk_fp8_f32(src[eo] * 16.0f, src[eo + 1] * 16.0f, 0, false);
    whh8[i] = (unsigned short)(p & 0xFFFF);
  } else {                                // wembed gather -> x[:,128:640]
    int gid = (bid - 6144) * 256 + threadIdx.x;
    int row = gid >> 6;
    int c8 = (gid & 63) * 8;
    int b = row & 63, t = row >> 6;
    int sent = sentence[b * 256 + t];
    const float* src = wemb + (long)sent * 512 + c8;
    u16x8 o;
    #pragma unroll
    for (int e = 0; e < 8; ++e) o[e] = f2bf(src[e]);
    *(u16x8*)&x[row * 640 + 128 + c8] = o;
  }
}

// ---------------- K1: fused char embed + char BiLSTM -> x[:,0:128] ---------
DEVI bf16x8 load_wfrag(const float* Wm, int rowbase, int l15, int lhi, int ks) {
  const float* p = Wm + (rowbase + l15) * 64 + ks * 32 + lhi * 8;
  u16x8 u;
  #pragma unroll
  for (int e = 0; e < 8; ++e) u[e] = f2bf(p[e]);
  return __builtin_bit_cast(bf16x8, u);
}

__launch_bounds__(256, 1)
__global__ void k_char_lstm(const int* chars, const float* cemb,
                            const float* cWih_f, const float* cWhh_f, const float* cb_f,
                            const float* cWih_b, const float* cWhh_b, const float* cb_b,
                            const float* h0c, const float* c0c,
                            unsigned short* x) {
  __shared__ unsigned short embT[128 * 64];
  __shared__ int charsT[16 * 64];
  __shared__ unsigned short hT[64 * 72];
  const int tid = threadIdx.x;
  const int w = tid >> 6, lane = tid & 63;
  const int l15 = lane & 15, lhi = lane >> 4;
  const int sbase = blockIdx.x * 64;

  for (int idx = tid; idx < 8192; idx += 256) embT[idx] = f2bf(cemb[idx]);
  for (int idx = tid; idx < 1024; idx += 256) {
    int s = idx >> 4, t = idx & 15;
    charsT[t * 64 + s] = chars[(sbase + s) * 16 + t];
  }
  for (int idx = tid; idx < 4096; idx += 256) {
    int s = idx >> 6, u = idx & 63;
    hT[s * 72 + u] = f2bf(h0c[(sbase + s) * 64 + u]);
  }
  bf16x8 bih[4][2], bhh[4][2];
  float bias[4];
  #pragma unroll
  for (int q = 0; q < 4; ++q) {
    bias[q] = cb_f[q * 64 + w * 16 + l15];
    #pragma unroll
    for (int ks = 0; ks < 2; ++ks) {
      bih[q][ks] = load_wfrag(cWih_f, (w + 4 * q) * 16, l15, lhi, ks);
      bhh[q][ks] = load_wfrag(cWhh_f, (w + 4 * q) * 16, l15, lhi, ks);
    }
  }
  float c_[4][4];
  #pragma unroll
  for (int mt = 0; mt < 4; ++mt)
    #pragma unroll
    for (int i = 0; i < 4; ++i)
      c_[mt][i] = c0c[(sbase + mt * 16 + lhi * 4 + i) * 64 + w * 16 + l15];
  float hfin[4][4];
  #pragma unroll
  for (int mt = 0; mt < 4; ++mt)
    #pragma unroll
    for (int i = 0; i < 4; ++i) hfin[mt][i] = 0.0f;
  __syncthreads();

  for (int t = 0; t < 16; ++t) {
    bf16x8 ax[4][2], ah[4][2];
    #pragma unroll
    for (int mt = 0; mt < 4; ++mt) {
      int cidx = charsT[t * 64 + mt * 16 + l15];
      #pragma unroll
      for (int ks = 0; ks < 2; ++ks) {
        ax[mt][ks] = __builtin_bit_cast(bf16x8, *(const u16x8*)&embT[cidx * 64 + ks * 32 + lhi * 8]);
        ah[mt][ks] = __builtin_bit_cast(bf16x8, *(const u16x8*)&hT[(mt * 16 + l15) * 72 + ks * 32 + lhi * 8]);
      }
    }
    f32x4 acc[4][4];
    #pragma unroll
    for (int mt = 0; mt < 4; ++mt)
      #pragma unroll
      for (int q = 0; q < 4; ++q) acc[mt][q] = (f32x4){0.f, 0.f, 0.f, 0.f};
    #pragma unroll
    for (int ks = 0; ks < 2; ++ks)
      #pragma unroll
      for (int mt = 0; mt < 4; ++mt)
        #pragma unroll
        for (int q = 0; q < 4; ++q) {
          acc[mt][q] = mfma_bf16(ax[mt][ks], bih[q][ks], acc[mt][q]);
          acc[mt][q] = mfma_bf16(ah[mt][ks], bhh[q][ks], acc[mt][q]);
        }
    __syncthreads();
    #pragma unroll
    for (int mt = 0; mt < 4; ++mt)
      #pragma unroll
      for (int i = 0; i < 4; ++i) {
        float gi = acc[mt][0][i] + bias[0];
        float gf = acc[mt][1][i] + bias[1];
        float gg = acc[mt][2][i] + bias[2];
        float go = acc[mt][3][i] + bias[3];
        float cn = sigf(gf) * c_[mt][i] + sigf(gi) * tanhf_(gg);
        float h = sigf(go) * tanhf_(cn);
        c_[mt][i] = cn;
        if (t == 15) hfin[mt][i] = h;
        hT[(mt * 16 + lhi * 4 + i) * 72 + w * 16 + l15] = f2bf(h);
      }
    __syncthreads();
  }
  #pragma unroll
  for (int mt = 0; mt < 4; ++mt)
    #pragma unroll
    for (int i = 0; i < 4; ++i) {
      int sg = sbase + mt * 16 + lhi * 4 + i;
      int xrow = (sg & 255) * 64 + (sg >> 8);
      x[xrow * 640 + w * 16 + l15] = f2bf(hfin[mt][i]);
    }
  #pragma unroll
  for (int q = 0; q < 4; ++q) {
    bias[q] = cb_b[q * 64 + w * 16 + l15];
    #pragma unroll
    for (int ks = 0; ks < 2; ++ks) {
      bih[q][ks] = load_wfrag(cWih_b, (w + 4 * q) * 16, l15, lhi, ks);
      bhh[q][ks] = load_wfrag(cWhh_b, (w + 4 * q) * 16, l15, lhi, ks);
    }
  }
  __syncthreads();
  for (int idx = tid; idx < 4096; idx += 256) {
    int s = idx >> 6, u = idx & 63;
    hT[s * 72 + u] = f2bf(h0c[16384 * 64 + (sbase + s) * 64 + u]);
  }
  __syncthreads();
  {
    bf16x8 ax[4][2], ah[4][2];
    #pragma unroll
    for (int mt = 0; mt < 4; ++mt) {
      int cidx = charsT[15 * 64 + mt * 16 + l15];
      #pragma unroll
      for (int ks = 0; ks < 2; ++ks) {
        ax[mt][ks] = __builtin_bit_cast(bf16x8, *(const u16x8*)&embT[cidx * 64 + ks * 32 + lhi * 8]);
        ah[mt][ks] = __builtin_bit_cast(bf16x8, *(const u16x8*)&hT[(mt * 16 + l15) * 72 + ks * 32 + lhi * 8]);
      }
    }
    f32x4 acc[4][4];
    #pragma unroll
    for (int mt = 0; mt < 4; ++mt)
      #pragma unroll
      for (int q = 0; q < 4; ++q) acc[mt][q] = (f32x4){0.f, 0.f, 0.f, 0.f};
    #pragma unroll
    for (int ks = 0; ks < 2; ++ks)
      #pragma unroll
      for (int mt = 0; mt < 4; ++mt)
        #pragma unroll
        for (int q = 0; q < 4; ++q) {
          acc[mt][q] = mfma_bf16(ax[mt][ks], bih[q][ks], acc[mt][q]);
          acc[mt][q] = mfma_bf16(ah[mt][ks], bhh[q][ks], acc[mt][q]);
        }
    #pragma unroll
    for (int mt = 0; mt < 4; ++mt)
      #pragma unroll
      for (int i = 0; i < 4; ++i) {
        float cc = c0c[16384 * 64 + (sbase + mt * 16 + lhi * 4 + i) * 64 + w * 16 + l15];
        float gi = acc[mt][0][i] + bias[0];
        float gf = acc[mt][1][i] + bias[1];
        float gg = acc[mt][2][i] + bias[2];
        float go = acc[mt][3][i] + bias[3];
        float cn = sigf(gf) * cc + sigf(gi) * tanhf_(gg);
        float h = sigf(go) * tanhf_(cn);
        int sg = sbase + mt * 16 + lhi * 4 + i;
        int xrow = (sg & 255) * 64 + (sg >> 8);
        x[xrow * 640 + 64 + w * 16 + l15] = f2bf(h);
      }
  }
}

// ---------------- K3: pre-gates GEMM  x[16384,640] @ wcat.T
// writes transposed pre2[rg8][t][col 2048][8 rows] bf16
__launch_bounds__(256, 2)
__global__ void k_gemm_pre(const unsigned short* x, const unsigned short* wcat,
                           const float* wb_f, const float* wb_b,
                           unsigned short* pre2) {
  __shared__ __align__(16) unsigned char lds3[2][2][16384];
  const int tid = threadIdx.x;
  const int bm = blockIdx.x & 127, bn = blockIdx.x >> 7;
  const int m0 = bm * 128, n0 = bn * 128;
  const int lane = tid & 63, w = tid >> 6;
  const int l15 = lane & 15, lhi = lane >> 4;
  const int wm = (w & 1) * 64, wn = (w >> 1) * 64;

  u16x8 ra[4], rb[4];
  auto gload = [&](int kt) {
    #pragma unroll
    for (int i = 0; i < 4; ++i) {
      int o = tid * 16 + i * 4096;
      int r = o >> 7, cb = o & 127;
      ra[i] = *(const u16x8*)&x[(m0 + r) * 640 + kt * 64 + (cb >> 1)];
      rb[i] = *(const u16x8*)&wcat[(n0 + r) * 640 + kt * 64 + (cb >> 1)];
    }
  };
  auto swrite = [&](int buf) {
    #pragma unroll
    for (int i = 0; i < 4; ++i) {
      int o = tid * 16 + i * 4096;
      int osw = o ^ (((o >> 7) & 7) << 4);
      *(u16x8*)(&lds3[buf][0][0] + osw) = ra[i];
      *(u16x8*)(&lds3[buf][1][0] + osw) = rb[i];
    }
  };
  f32x4 acc[4][4];
  #pragma unroll
  for (int a = 0; a < 4; ++a)
    #pragma unroll
    for (int bb = 0; bb < 4; ++bb) acc[a][bb] = (f32x4){0.f, 0.f, 0.f, 0.f};

  gload(0); swrite(0); __syncthreads();
  for (int kt = 0; kt < 10; ++kt) {
    int cur = kt & 1;
    if (kt < 9) gload(kt + 1);
    #pragma unroll
    for (int ks = 0; ks < 2; ++ks) {
      bf16x8 af[4], bfv[4];
      #pragma unroll
      for (int mt = 0; mt < 4; ++mt) {
        int o = (wm + mt * 16 + l15) * 128 + ks * 64 + lhi * 16;
        o ^= ((o >> 7) & 7) << 4;
        af[mt] = __builtin_bit_cast(bf16x8, *(const u16x8*)(&lds3[cur][0][0] + o));
      }
      #pragma unroll
      for (int nt = 0; nt < 4; ++nt) {
        int o = (wn + nt * 16 + l15) * 128 + ks * 64 + lhi * 16;
        o ^= ((o >> 7) & 7) << 4;
        bfv[nt] = __builtin_bit_cast(bf16x8, *(const u16x8*)(&lds3[cur][1][0] + o));
      }
      #pragma unroll
      for (int mt = 0; mt < 4; ++mt)
        #pragma unroll
        for (int nt = 0; nt < 4; ++nt)
          acc[mt][nt] = mfma_bf16(af[mt], bfv[nt], acc[mt][nt]);
    }
    __syncthreads();
    if (kt < 9) { swrite(cur ^ 1); __syncthreads(); }
  }
  // epilogue: transposed store, 4 rows (=4 i) packed per 8B
  #pragma unroll
  for (int nt = 0; nt < 4; ++nt) {
    int col = n0 + wn + nt * 16 + l15;
    float bias = (col < 1024) ? wb_f[col] : wb_b[col - 1024];
    #pragma unroll
    for (int mt = 0; mt < 4; ++mt) {
      int row = m0 + wm + mt * 16 + lhi * 4;    // +i, i=0..3 consecutive
      int t = row >> 6, b = row & 63, rg = b >> 3, b8 = b & 7;
      u16x4 v;
      #pragma unroll
      for (int i = 0; i < 4; ++i) v[i] = f2bf(acc[mt][nt][i] + bias);
      *(u16x4*)&pre2[((long)(rg * 256 + t) * 2048 + col) * 8 + b8] = v;
    }
  }
}

// ---------------- K4: word LSTM recurrence v6 (4 rows/block, M-sparse) -----
// 32 blocks (2 dir x 16 rowgroups of 4 rows), 16 waves. Batch row r stored at
// M-position 4r in hlds -> C/D acc[g][0] at lane(l15,lhi) is exactly
// (row=lhi, unit=w*16+l15): ONE gate-tuple per thread, zero cross-lane ops.
#define LSTM_STEP(SRC, DST, PU, TT)                                          \
  {                                                                          \
    long a8[8];                                                              \
    _Pragma("unroll")                                                        \
    for (int ks = 0; ks < 8; ++ks)                                           \
      a8[ks] = *(const long*)&SRC[l15 * 264 + ks * 32 + lhi * 8];            \
    l64x4 alo4 = {a8[0], a8[1], a8[2], a8[3]};                               \
    l64x4 ahi4 = {a8[4], a8[5], a8[6], a8[7]};                               \
    i32x8 aLo = __builtin_bit_cast(i32x8, alo4);                             \
    i32x8 aHi = __builtin_bit_cast(i32x8, ahi4);                             \
    f32x4 acc[4];                                                            \
    _Pragma("unroll")                                                        \
    for (int g = 0; g < 4; ++g) acc[g] = (f32x4){0.f, 0.f, 0.f, 0.f};        \
    _Pragma("unroll")                                                        \
    for (int g = 0; g < 4; ++g) {                                            \
      acc[g] = mfma_mx(aLo, bfr2[g][0], acc[g]);                             \
      acc[g] = mfma_mx(aHi, bfr2[g][1], acc[g]);                             \
    }                                                                        \
    float gi = fmaf(acc[0][0], inv, bf2f(PU[0]));                            \
    float gf = fmaf(acc[1][0], inv, bf2f(PU[1]));                            \
    float gg = fmaf(acc[2][0], inv, bf2f(PU[2]));                            \
    float go = fmaf(acc[3][0], inv, bf2f(PU[3]));                            \
    float cn = sigf(gf) * c1 + sigf(gi) * tanhf_(gg);                        \
    float h = sigf(go) * tanhf_(cn);                                         \
    c1 = cn;                                                                 \
    int p2 = __builtin_amdgcn_cvt_pk_fp8_f32(h * 16.0f, 0.0f, 0, false);     \
    DST[(4 * lhi) * 264 + uu] = (unsigned char)(p2 & 0xFF);                  \
    hout[((long)(TT) * 64 + row0 + lhi) * 512 + dco] = f2bf(h);              \
  }

__launch_bounds__(1024, 4)
__global__ void k_word_lstm(const unsigned char* whh8, const unsigned short* pre2,
                            const float* h0w, const float* c0w,
                            unsigned short* hout) {
  __shared__ __align__(16) unsigned char hlds[2][16 * 264];   // fp8 h, x16 scale
  const int tid = threadIdx.x;
  const int w = tid >> 6, lane = tid & 63;
  const int l15 = lane & 15, lhi = lane >> 4;
  const int dir = blockIdx.x >> 4, rg = blockIdx.x & 15;
  const int row0 = rg * 4;
  const int uu = w * 16 + l15;
  const int dco = dir * 256 + uu;
  const unsigned char* W = whh8 + dir * 262144;

  i32x8 bfr2[4][2];   // resident fp8 weights, repacked for K=128 MFMA
  #pragma unroll
  for (int g = 0; g < 4; ++g) {
    int grow = g * 256 + uu;
    #pragma unroll
    for (int kt = 0; kt < 2; ++kt) {
      long t0 = *(const long*)(W + grow * 256 + (kt * 4 + 0) * 32 + lhi * 8);
      long t1 = *(const long*)(W + grow * 256 + (kt * 4 + 1) * 32 + lhi * 8);
      long t2 = *(const long*)(W + grow * 256 + (kt * 4 + 2) * 32 + lhi * 8);
      long t3 = *(const long*)(W + grow * 256 + (kt * 4 + 3) * 32 + lhi * 8);
      l64x4 v = {t0, t1, t2, t3};
      bfr2[g][kt] = __builtin_bit_cast(i32x8, v);
    }
  }
  // zero BOTH buffers fully, then fill buf0 real rows (M rows 0,4,8,12)
  for (int idx = tid; idx < 2112; idx += 1024)
    ((unsigned int*)&hlds[0][0])[idx] = 0;
  __syncthreads();
  {
    int r = tid >> 8, u0 = tid & 255;
    float hv = h0w[dir * 16384 + (row0 + r) * 256 + u0];
    int p = __builtin_amdgcn_cvt_pk_fp8_f32(hv * 16.0f, 0.0f, 0, false);
    hlds[0][(4 * r) * 264 + u0] = (unsigned char)(p & 0xFF);
  }
  float c1 = c0w[dir * 16384 + (row0 + lhi) * 256 + uu];

  // pre2 source base: index = ((rg8*256+t)*2048 + dir*1024 + g*256 + uu)*8 + b8
  const unsigned short* pgBase =
      pre2 + (long)(rg >> 1) * 256 * 2048 * 8 + (dir * 1024 + uu) * 8 + (rg & 1) * 4 + lhi;

  unsigned short pA[4], pB[4];
  const int ttA0 = dir ? 255 : 0;
  #pragma unroll
  for (int g = 0; g < 4; ++g)
    pA[g] = pgBase[(long)ttA0 * 16384 + g * 2048];
  __syncthreads();

  const float inv = 1.0f / 256.0f;
  for (int t = 0; t < 256; t += 2) {
    const int ttA = dir ? (255 - t) : t;
    const int ttB = dir ? (254 - t) : (t + 1);
    int ttC = dir ? (253 - t) : (t + 2);
    ttC = ttC < 0 ? 0 : (ttC > 255 ? 255 : ttC);
    // ---- step A: hlds[0] -> hlds[1], gates pA, prefetch pB(ttB) ----
    #pragma unroll
    for (int g = 0; g < 4; ++g)
      pB[g] = pgBase[(long)ttB * 16384 + g * 2048];
    LSTM_STEP(hlds[0], hlds[1], pA, ttA)
    lds_barrier();
    // ---- step B: hlds[1] -> hlds[0], gates pB, prefetch pA(ttC) ----
    #pragma unroll
    for (int g = 0; g < 4; ++g)
      pA[g] = pgBase[(long)ttC * 16384 + g * 2048];
    LSTM_STEP(hlds[1], hlds[0], pB, ttB)
    lds_barrier();
  }
}

// ---------------- K5: feats = h @ Wtag.T + btag  (N=12 padded to 16) -------
__launch_bounds__(256, 2)
__global__ void k_feats(const unsigned short* hbuf, const float* Wtag, const float* btag,
                        float* feats) {
  const int tid = threadIdx.x;
  const int w = tid >> 6, lane = tid & 63, l15 = lane & 15, lhi = lane >> 4;
  const int m0 = blockIdx.x * 64 + w * 16;
  bf16x8 bfr[16];
  #pragma unroll
  for (int ks = 0; ks < 16; ++ks) {
    u16x8 u;
    if (l15 < 12) {
      const float* p = Wtag + l15 * 512 + ks * 32 + lhi * 8;
      #pragma unroll
      for (int e = 0; e < 8; ++e) u[e] = f2bf(p[e]);
    } else {
      #pragma unroll
      for (int e = 0; e < 8; ++e) u[e] = 0;
    }
    bfr[ks] = __builtin_bit_cast(bf16x8, u);
  }
  f32x4 acc = {0.f, 0.f, 0.f, 0.f};
  #pragma unroll
  for (int ks = 0; ks < 16; ++ks) {
    u16x8 a = *(const u16x8*)&hbuf[(m0 + l15) * 512 + ks * 32 + lhi * 8];
    acc = mfma_bf16(__builtin_bit_cast(bf16x8, a), bfr[ks], acc);
  }
  float bias = (l15 < 12) ? btag[l15] : 0.0f;
  #pragma unroll
  for (int i = 0; i < 4; ++i)
    feats[(m0 + lhi * 4 + i) * 16 + l15] = acc[i] + bias;
}

// ---------------- K6: CRF forward + gold + loss ----------------------------
__launch_bounds__(1024, 1)
__global__ void k_crf(const float* feats, const float* trans, const int* tags, float* out) {
  __shared__ float alpha[2][64 * 16];
  __shared__ float red[1024];
  const int tid = threadIdx.x;
  const int j = tid & 15, b = tid >> 4;
  float tr[12];
  if (j < 12) {
    #pragma unroll
    for (int i = 0; i < 12; ++i) tr[i] = trans[j * 12 + i];
  }
  alpha[0][b * 16 + j] = (j == 0) ? 0.0f : -10000.0f;
  __syncthreads();
  int cur = 0;
  for (int t = 0; t < 256; ++t) {
    if (j < 12) {
      float s_[12], m = -3.4e38f;
      #pragma unroll
      for (int i = 0; i < 12; ++i) { s_[i] = alpha[cur][b * 16 + i] + tr[i]; m = fmaxf(m, s_[i]); }
      float sum = 0.f;
      #pragma unroll
      for (int i = 0; i < 12; ++i) sum += __expf(s_[i] - m);
      alpha[cur ^ 1][b * 16 + j] = m + __logf(sum) + feats[t * 1024 + b * 16 + j];
    }
    __syncthreads();
    cur ^= 1;
  }
  float part = 0.0f;
  if (tid < 64) {
    float s_[12], m = -3.4e38f;
    #pragma unroll
    for (int i = 0; i < 12; ++i) { s_[i] = alpha[cur][tid * 16 + i] + trans[2 * 12 + i]; m = fmaxf(m, s_[i]); }
    float sum = 0.f;
    #pragma unroll
    for (int i = 0; i < 12; ++i) sum += __expf(s_[i] - m);
    part = m + __logf(sum);
  }
  for (int idx = tid; idx < 16384; idx += 1024) {
    int t = idx >> 6, bb = idx & 63;
    int tg = tags[bb * 256 + t];
    int pv = (t == 0) ? 0 : tags[bb * 256 + t - 1];
    float g = feats[t * 1024 + bb * 16 + tg] + trans[tg * 12 + pv];
    if (t == 255) g += trans[2 * 12 + tg];
    part -= g;
  }
  red[tid] = part;
  __syncthreads();
  for (int st = 512; st > 0; st >>= 1) {
    if (tid < st) red[tid] += red[tid + st];
    __syncthreads();
  }
  if (tid == 0) out[0] = red[0] / 64.0f;
}

// ---------------------------------------------------------------------------
extern "C" void kernel_launch(void* const* d_in, const int* in_sizes, int n_in,
                              void* d_out, int out_size, void* d_ws, size_t ws_size,
                              hipStream_t stream) {
  const int*   sentence = (const int*)d_in[0];
  const int*   chars    = (const int*)d_in[1];
  const int*   tags     = (const int*)d_in[2];
  const float* wemb     = (const float*)d_in[3];
  const float* cemb     = (const float*)d_in[4];
  const float* cWih_f   = (const float*)d_in[5];
  const float* cWhh_f   = (const float*)d_in[6];
  const float* cb_f     = (const float*)d_in[7];
  const float* cWih_b   = (const float*)d_in[8];
  const float* cWhh_b   = (const float*)d_in[9];
  const float* cb_b     = (const float*)d_in[10];
  const float* wWih_f   = (const float*)d_in[11];
  const float* wWhh_f   = (const float*)d_in[12];
  const float* wb_f     = (const float*)d_in[13];
  const float* wWih_b   = (const float*)d_in[14];
  const float* wWhh_b   = (const float*)d_in[15];
  const float* wb_b     = (const float*)d_in[16];
  const float* Wtag     = (const float*)d_in[17];
  const float* btag     = (const float*)d_in[18];
  const float* trans    = (const float*)d_in[19];
  const float* h0c      = (const float*)d_in[20];
  const float* c0c      = (const float*)d_in[21];
  const float* h0w      = (const float*)d_in[22];
  const float* c0w      = (const float*)d_in[23];

  char* ws = (char*)d_ws;
  unsigned short* x     = (unsigned short*)(ws);
  unsigned short* pre2  = (unsigned short*)(ws + 20971520);
  unsigned short* hbuf  = (unsigned short*)(ws + 88080384);
  float*          feats = (float*)(ws + 104857600);
  unsigned short* wcat  = (unsigned short*)(ws + 105906176);
  unsigned short* whh8  = (unsigned short*)(ws + 108527616);

  hipLaunchKernelGGL(k_prep, dim3(10240), dim3(256), 0, stream,
                     wWih_f, wWih_b, wWhh_f, wWhh_b, sentence, wemb, wcat, whh8, x);
  hipLaunchKernelGGL(k_char_lstm, dim3(256), dim3(256), 0, stream, chars, cemb,
                     cWih_f, cWhh_f, cb_f, cWih_b, cWhh_b, cb_b, h0c, c0c, x);
  hipLaunchKernelGGL(k_gemm_pre, dim3(2048), dim3(256), 0, stream, x, wcat, wb_f, wb_b, pre2);
  hipLaunchKernelGGL(k_word_lstm, dim3(32), dim3(1024), 0, stream,
                     (const unsigned char*)whh8, pre2, h0w, c0w, hbuf);
  hipLaunchKernelGGL(k_feats, dim3(256), dim3(256), 0, stream, hbuf, Wtag, btag, feats);
  hipLaunchKernelGGL(k_crf, dim3(1), dim3(1024), 0, stream, feats, trans, tags, (float*)d_out);
}